// Round 1
// baseline (4597.787 us; speedup 1.0000x reference)
//
#include <hip/hip_runtime.h>
#include <math.h>

typedef unsigned short u16;
typedef __attribute__((ext_vector_type(8))) __bf16 bf16x8;
typedef __attribute__((ext_vector_type(4))) float f32x4;
typedef __attribute__((ext_vector_type(4))) u16 u16x4;

#define DIM    2048
#define NLAT   256
#define HEADS  8
#define DHEAD  64
#define INNER  512
#define TT     24
#define NN     49
#define SEQ    (TT*NN)        // 1176
#define BATCH  16
#define MROWS  (BATCH*SEQ)    // 18816
#define LROWS  (BATCH*NLAT)   // 4096
#define KEYS   (SEQ+NLAT)     // 1432
#define FF     (DIM*4)        // 8192
#define SCALE  0.125f

__device__ __forceinline__ u16 f2bf(float f) {
  union { float f; unsigned u; } c; c.f = f;
  unsigned r = c.u + 0x7FFFu + ((c.u >> 16) & 1u);
  return (u16)(r >> 16);
}

// ---------------------------------------------------------------------------
// Weight transpose + fp32->bf16: W (K x N) -> Wt (N x K) bf16
// ---------------------------------------------------------------------------
__global__ __launch_bounds__(256) void transpose_bf16(
    const float* __restrict__ W, u16* __restrict__ Wt, int K, int N)
{
  __shared__ float tile[32][33];
  const int tx = threadIdx.x & 31, ty = threadIdx.x >> 5;   // 32 x 8
  const int n0 = blockIdx.x * 32, k0 = blockIdx.y * 32;
  #pragma unroll
  for (int p = 0; p < 4; ++p)
    tile[ty + p*8][tx] = W[(size_t)(k0 + ty + p*8) * N + n0 + tx];
  __syncthreads();
  #pragma unroll
  for (int p = 0; p < 4; ++p)
    Wt[(size_t)(n0 + ty + p*8) * K + k0 + tx] = f2bf(tile[tx][ty + p*8]);
}

// ---------------------------------------------------------------------------
// LayerNorm over rows of length DIM. OUT = u16 (bf16) or float.
// ---------------------------------------------------------------------------
template<typename OUT>
__global__ __launch_bounds__(256) void ln_row(
    const float* __restrict__ x, const float* __restrict__ s,
    const float* __restrict__ b, OUT* __restrict__ y)
{
  const size_t row = blockIdx.x;
  const int tid = threadIdx.x;
  const f32x4* xr = (const f32x4*)(x + row * DIM);
  f32x4 v0 = xr[tid], v1 = xr[tid + 256];
  float sum = v0[0]+v0[1]+v0[2]+v0[3] + v1[0]+v1[1]+v1[2]+v1[3];
  float sq  = v0[0]*v0[0]+v0[1]*v0[1]+v0[2]*v0[2]+v0[3]*v0[3]
            + v1[0]*v1[0]+v1[1]*v1[1]+v1[2]*v1[2]+v1[3]*v1[3];
  #pragma unroll
  for (int o = 32; o > 0; o >>= 1) { sum += __shfl_down(sum, o); sq += __shfl_down(sq, o); }
  __shared__ float red[18];
  const int wave = tid >> 6, lane = tid & 63;
  if (lane == 0) { red[wave] = sum; red[8 + wave] = sq; }
  __syncthreads();
  if (tid == 0) {
    float S = red[0]+red[1]+red[2]+red[3];
    float Q = red[8]+red[9]+red[10]+red[11];
    float m = S * (1.0f/DIM);
    float var = Q * (1.0f/DIM) - m*m;
    red[16] = m; red[17] = rsqrtf(var + 1e-5f);
  }
  __syncthreads();
  const float m = red[16], inv = red[17];
  const f32x4* s4 = (const f32x4*)s; const f32x4* b4 = (const f32x4*)b;
  f32x4 o0 = (v0 - m) * inv * s4[tid]       + b4[tid];
  f32x4 o1 = (v1 - m) * inv * s4[tid + 256] + b4[tid + 256];
  if (sizeof(OUT) == 2) {
    u16x4 a = {f2bf(o0[0]), f2bf(o0[1]), f2bf(o0[2]), f2bf(o0[3])};
    u16x4 c = {f2bf(o1[0]), f2bf(o1[1]), f2bf(o1[2]), f2bf(o1[3])};
    u16x4* yr = (u16x4*)((u16*)y + row * DIM);
    yr[tid] = a; yr[tid + 256] = c;
  } else {
    f32x4* yr = (f32x4*)((float*)y + row * DIM);
    yr[tid] = o0; yr[tid + 256] = o1;
  }
}

// ---------------------------------------------------------------------------
// bf16 MFMA GEMM, m97 structure: 128x128 tile, BK=32, global_load_lds w=16.
// A: M x K bf16 row-major.  Bt: N x K bf16 row-major (B transposed).
// EPI: 0 = f32 C;  1 = f32 C + seg_emb[(row%1176)/49];  2 = f32 C + res;
//      3 = bf16 C = gelu_exact(AB).
// M, N multiples of 128; K multiple of 32.
// ---------------------------------------------------------------------------
template<int EPI>
__global__ __launch_bounds__(256) void gemm_bf16(
    const u16* __restrict__ A, const u16* __restrict__ Bt, void* __restrict__ Cv,
    const float* __restrict__ res, const float* __restrict__ seg,
    int M, int N, int K)
{
  __shared__ u16 lA[128 * 32];
  __shared__ u16 lB[128 * 32];
  const int tid  = threadIdx.x;
  const int wave = tid >> 6, lane = tid & 63;
  const int rowBase = blockIdx.y * 128, colBase = blockIdx.x * 128;
  const int wr = (wave >> 1) * 64, wc = (wave & 1) * 64;
  const int quad = lane >> 4, l16 = lane & 15;
  const int srow = lane >> 2, chunk = lane & 3;   // staging row-in-seg / 8-elem chunk

  f32x4 acc[4][4] = {};

  for (int k0 = 0; k0 < K; k0 += 32) {
    #pragma unroll
    for (int c = 0; c < 2; ++c) {
      const int seg16 = wave * 2 + c;                 // 0..7, wave-uniform
      const int row = seg16 * 16 + srow;
      const u16* gA = A  + (size_t)(rowBase + row) * K + k0 + chunk * 8;
      const u16* gB = Bt + (size_t)(colBase + row) * K + k0 + chunk * 8;
      __builtin_amdgcn_global_load_lds(
          (__attribute__((address_space(1))) void*)gA,
          (__attribute__((address_space(3))) void*)&lA[seg16 * 512], 16, 0, 0);
      __builtin_amdgcn_global_load_lds(
          (__attribute__((address_space(1))) void*)gB,
          (__attribute__((address_space(3))) void*)&lB[seg16 * 512], 16, 0, 0);
    }
    __syncthreads();
    bf16x8 af[4], bf[4];
    #pragma unroll
    for (int i = 0; i < 4; ++i)
      af[i] = *(const bf16x8*)&lA[(wr + i*16 + l16) * 32 + quad * 8];
    #pragma unroll
    for (int j = 0; j < 4; ++j)
      bf[j] = *(const bf16x8*)&lB[(wc + j*16 + l16) * 32 + quad * 8];
    #pragma unroll
    for (int i = 0; i < 4; ++i)
      #pragma unroll
      for (int j = 0; j < 4; ++j)
        acc[i][j] = __builtin_amdgcn_mfma_f32_16x16x32_bf16(af[i], bf[j], acc[i][j], 0, 0, 0);
    __syncthreads();
  }

  #pragma unroll
  for (int i = 0; i < 4; ++i) {
    #pragma unroll
    for (int j = 0; j < 4; ++j) {
      const int col = colBase + wc + j*16 + l16;
      #pragma unroll
      for (int r = 0; r < 4; ++r) {
        const int row = rowBase + wr + i*16 + quad*4 + r;
        const size_t idx = (size_t)row * N + col;
        float val = acc[i][j][r];
        if (EPI == 0) {
          ((float*)Cv)[idx] = val;
        } else if (EPI == 1) {
          const int t = (row % SEQ) / NN;
          ((float*)Cv)[idx] = val + seg[t * DIM + col];
        } else if (EPI == 2) {
          ((float*)Cv)[idx] = val + res[idx];
        } else {
          float g = 0.5f * val * (1.0f + erff(val * 0.70710678118f));
          ((u16*)Cv)[idx] = f2bf(g);
        }
      }
    }
  }
}

// ---------------------------------------------------------------------------
// Stage-A windowed attention: per (b,t), 8 heads x 49 queries over 49 keys.
// Q fp32 (MROWS x 512), KV fp32 (MROWS x 1024, k=0..511 v=512..1023).
// Out bf16 (MROWS x 512). Softmax without max-subtraction (|sim| small).
// ---------------------------------------------------------------------------
__global__ __launch_bounds__(512) void attn_local(
    const float* __restrict__ Q, const float* __restrict__ KV, u16* __restrict__ out)
{
  const int b = blockIdx.x / TT, t = blockIdx.x % TT;
  const int h = threadIdx.x >> 6, qi = threadIdx.x & 63;
  if (qi >= NN) return;
  const size_t rowq = (size_t)b * SEQ + t * NN + qi;
  const f32x4* qr = (const f32x4*)(Q + rowq * INNER + h * DHEAD);
  f32x4 qv[16];
  #pragma unroll
  for (int d = 0; d < 16; ++d) qv[d] = qr[d] * SCALE;
  f32x4 ov[16] = {};
  float l = 0.f;
  const float* kvbase = KV + ((size_t)b * SEQ + t * NN) * 1024 + h * DHEAD;
  for (int j = 0; j < NN; ++j) {
    const f32x4* kr = (const f32x4*)(kvbase + (size_t)j * 1024);
    const f32x4* vr = (const f32x4*)(kvbase + (size_t)j * 1024 + INNER);
    float s = 0.f;
    #pragma unroll
    for (int d = 0; d < 16; ++d) {
      f32x4 k4 = kr[d];
      s += qv[d][0]*k4[0] + qv[d][1]*k4[1] + qv[d][2]*k4[2] + qv[d][3]*k4[3];
    }
    float e = __expf(s);
    l += e;
    #pragma unroll
    for (int d = 0; d < 16; ++d) ov[d] += e * vr[d];
  }
  const float rl = 1.0f / l;
  u16* orow = out + rowq * INNER + h * DHEAD;
  #pragma unroll
  for (int d = 0; d < 16; ++d) {
    f32x4 o = ov[d] * rl;
    u16x4 u = {f2bf(o[0]), f2bf(o[1]), f2bf(o[2]), f2bf(o[3])};
    *(u16x4*)(orow + d * 4) = u;
  }
}

// ---------------------------------------------------------------------------
// Cross-attention, flash-decode style. Partial over key-split sp (358 keys).
// Q fp32 (LROWS x 512); KX fp32 (MROWS x 1024); KL fp32 (LROWS x 1024).
// OP: per query-group raw o-sums (32768 x 4 x 64); LP: raw l (32768 x 4).
// ---------------------------------------------------------------------------
#define KSPLIT 4
#define KPS    (KEYS / KSPLIT)   // 358

__global__ __launch_bounds__(256) void attn_cross_part(
    const float* __restrict__ Q, const float* __restrict__ KX,
    const float* __restrict__ KL, float* __restrict__ OP, float* __restrict__ LP)
{
  const int b = blockIdx.x, h = blockIdx.y, sp = blockIdx.z;
  const int qi = threadIdx.x;
  __shared__ float lk[16 * 64], lv[16 * 64];
  const f32x4* qr = (const f32x4*)(Q + ((size_t)b * NLAT + qi) * INNER + h * DHEAD);
  f32x4 qv[16];
  #pragma unroll
  for (int d = 0; d < 16; ++d) qv[d] = qr[d] * SCALE;
  f32x4 ov[16] = {};
  float l = 0.f;
  const int j0 = sp * KPS, j1 = j0 + KPS;
  const int jj = threadIdx.x >> 4, d4s = threadIdx.x & 15;
  for (int jt = j0; jt < j1; jt += 16) {
    const int cnt = min(16, j1 - jt);
    if (jj < cnt) {
      const int j = jt + jj;
      const float* src = (j < SEQ)
          ? KX + ((size_t)b * SEQ + j) * 1024 + h * DHEAD
          : KL + ((size_t)b * NLAT + (j - SEQ)) * 1024 + h * DHEAD;
      ((f32x4*)lk)[jj * 16 + d4s] = ((const f32x4*)src)[d4s];
      ((f32x4*)lv)[jj * 16 + d4s] = ((const f32x4*)(src + INNER))[d4s];
    }
    __syncthreads();
    for (int u = 0; u < cnt; ++u) {
      const f32x4* kr = (const f32x4*)&lk[u * 64];
      const f32x4* vr = (const f32x4*)&lv[u * 64];
      float s = 0.f;
      #pragma unroll
      for (int d = 0; d < 16; ++d) {
        f32x4 k4 = kr[d];
        s += qv[d][0]*k4[0] + qv[d][1]*k4[1] + qv[d][2]*k4[2] + qv[d][3]*k4[3];
      }
      float e = __expf(s);
      l += e;
      #pragma unroll
      for (int d = 0; d < 16; ++d) ov[d] += e * vr[d];
    }
    __syncthreads();
  }
  const size_t qg = ((size_t)b * HEADS + h) * NLAT + qi;
  f32x4* op = (f32x4*)(OP + qg * (KSPLIT * DHEAD) + sp * DHEAD);
  #pragma unroll
  for (int d = 0; d < 16; ++d) op[d] = ov[d];
  LP[qg * KSPLIT + sp] = l;
}

__global__ __launch_bounds__(256) void attn_cross_comb(
    const float* __restrict__ OP, const float* __restrict__ LP, u16* __restrict__ out)
{
  const size_t g = (size_t)blockIdx.x * 256 + threadIdx.x; // over 32768*64
  const size_t qg = g >> 6;
  const int d = (int)(g & 63);
  const float* lp = LP + qg * KSPLIT;
  const float l = lp[0] + lp[1] + lp[2] + lp[3];
  const float* op = OP + qg * (KSPLIT * DHEAD) + d;
  const float o = op[0] + op[64] + op[128] + op[192];
  const int b = (int)(qg >> 11), h = (int)((qg >> 8) & 7), qi = (int)(qg & 255);
  out[((size_t)b * NLAT + qi) * INNER + h * DHEAD + d] = f2bf(o / l);
}

// ---------------------------------------------------------------------------
// lat init: lat[b*256+i][:] = latents[i][:]
// ---------------------------------------------------------------------------
__global__ __launch_bounds__(256) void lat_init(
    const float* __restrict__ latents, float* __restrict__ lat)
{
  const size_t i = (size_t)blockIdx.x * 256 + threadIdx.x;  // f32x4 units
  const size_t row = i >> 9, c4 = i & 511;
  ((f32x4*)lat)[i] = ((const f32x4*)latents)[(row & (NLAT - 1)) * 512 + c4];
}

// ---------------------------------------------------------------------------
// Launcher.  Workspace layout (~610 MB).
// ---------------------------------------------------------------------------
extern "C" void kernel_launch(void* const* d_in, const int* in_sizes, int n_in,
                              void* d_out, int out_size, void* d_ws, size_t ws_size,
                              hipStream_t stream) {
  const float* x        = (const float*)d_in[0];
  const float* g_norm_s = (const float*)d_in[1];
  const float* g_norm_b = (const float*)d_in[2];
  const float* g_wq     = (const float*)d_in[3];
  const float* g_wkv    = (const float*)d_in[4];
  const float* g_wo     = (const float*)d_in[5];
  const float* seg_emb  = (const float*)d_in[6];
  const float* latents  = (const float*)d_in[7];
  const float* a_nm_s   = (const float*)d_in[8];
  const float* a_nm_b   = (const float*)d_in[9];
  const float* a_nl_s   = (const float*)d_in[10];
  const float* a_nl_b   = (const float*)d_in[11];
  const float* a_wq     = (const float*)d_in[12];
  const float* a_wkv    = (const float*)d_in[13];
  const float* a_wo     = (const float*)d_in[14];
  const float* f_n_s    = (const float*)d_in[15];
  const float* f_n_b    = (const float*)d_in[16];
  const float* f_w1     = (const float*)d_in[17];
  const float* f_w2     = (const float*)d_in[18];
  const float* out_n_s  = (const float*)d_in[19];
  const float* out_n_b  = (const float*)d_in[20];

  size_t off = 0;
  auto alloc = [&](size_t bytes) -> char* {
    char* p = (char*)d_ws + off;
    off += (bytes + 255) & ~(size_t)255;
    return p;
  };
  float* XBUF  = (float*)alloc((size_t)MROWS * DIM * 4);   // x after stage A (fp32)
  u16*   TBUF  = (u16*)  alloc((size_t)MROWS * DIM * 2);   // LN(x) bf16
  u16*   LMBUF = (u16*)  alloc((size_t)LROWS * DIM * 2);   // LN(lat) bf16
  float* LAT   = (float*)alloc((size_t)LROWS * DIM * 4);
  float* QBUF  = (float*)alloc((size_t)MROWS * INNER * 4);
  float* KVX   = (float*)alloc((size_t)MROWS * 2 * INNER * 4);
  float* KVL   = (float*)alloc((size_t)LROWS * 2 * INNER * 4);
  u16*   AOBUF = (u16*)  alloc((size_t)MROWS * INNER * 2); // attn out bf16
  u16*   WT    = (u16*)  alloc((size_t)37748736 * 2);      // transposed weights
  float* OPART = (float*)alloc((size_t)32768 * KSPLIT * DHEAD * 4);
  float* LPART = (float*)alloc((size_t)32768 * KSPLIT * 4);
  u16*   HBUF  = (u16*)  alloc((size_t)LROWS * FF * 2);    // FFN hidden bf16
  (void)ws_size; (void)n_in; (void)in_sizes; (void)out_size;

  u16* WQT  = WT;                       // 512  x 2048
  u16* WKVT = WT + 1048576;             // 1024 x 2048
  u16* WOT  = WT + 3145728;             // 2048 x 512
  u16* W1T  = WT + 4194304;             // 8192 x 2048
  u16* W2T  = WT + 20971520;            // 2048 x 8192

  const dim3 b256(256);

  // ---- Stage A: global windowed attention ----
  transpose_bf16<<<dim3(INNER/32, DIM/32), b256, 0, stream>>>(g_wq,  WQT,  DIM, INNER);
  transpose_bf16<<<dim3(2*INNER/32, DIM/32), b256, 0, stream>>>(g_wkv, WKVT, DIM, 2*INNER);
  transpose_bf16<<<dim3(DIM/32, INNER/32), b256, 0, stream>>>(g_wo,  WOT,  INNER, DIM);
  ln_row<u16><<<MROWS, b256, 0, stream>>>(x, g_norm_s, g_norm_b, TBUF);
  gemm_bf16<0><<<dim3(INNER/128, MROWS/128), b256, 0, stream>>>(TBUF, WQT, QBUF, nullptr, nullptr, MROWS, INNER, DIM);
  gemm_bf16<0><<<dim3(2*INNER/128, MROWS/128), b256, 0, stream>>>(TBUF, WKVT, KVX, nullptr, nullptr, MROWS, 2*INNER, DIM);
  attn_local<<<BATCH*TT, dim3(512), 0, stream>>>(QBUF, KVX, AOBUF);
  gemm_bf16<1><<<dim3(DIM/128, MROWS/128), b256, 0, stream>>>(AOBUF, WOT, XBUF, nullptr, seg_emb, MROWS, DIM, INNER);
  lat_init<<<(LROWS*DIM/4)/256, b256, 0, stream>>>(latents, LAT);

  // ---- DEPTH cross-attention + FFN layers ----
  for (int l = 0; l < 3; ++l) {
    transpose_bf16<<<dim3(INNER/32, DIM/32), b256, 0, stream>>>(a_wq + (size_t)l*DIM*INNER, WQT, DIM, INNER);
    transpose_bf16<<<dim3(2*INNER/32, DIM/32), b256, 0, stream>>>(a_wkv + (size_t)l*DIM*2*INNER, WKVT, DIM, 2*INNER);
    transpose_bf16<<<dim3(DIM/32, INNER/32), b256, 0, stream>>>(a_wo + (size_t)l*INNER*DIM, WOT, INNER, DIM);
    transpose_bf16<<<dim3(FF/32, DIM/32), b256, 0, stream>>>(f_w1 + (size_t)l*DIM*FF, W1T, DIM, FF);
    transpose_bf16<<<dim3(DIM/32, FF/32), b256, 0, stream>>>(f_w2 + (size_t)l*FF*DIM, W2T, FF, DIM);

    ln_row<u16><<<MROWS, b256, 0, stream>>>(XBUF, a_nm_s + l*DIM, a_nm_b + l*DIM, TBUF);
    ln_row<u16><<<LROWS, b256, 0, stream>>>(LAT, a_nl_s + l*DIM, a_nl_b + l*DIM, LMBUF);

    gemm_bf16<0><<<dim3(INNER/128, LROWS/128), b256, 0, stream>>>(LMBUF, WQT, QBUF, nullptr, nullptr, LROWS, INNER, DIM);
    gemm_bf16<0><<<dim3(2*INNER/128, MROWS/128), b256, 0, stream>>>(TBUF, WKVT, KVX, nullptr, nullptr, MROWS, 2*INNER, DIM);
    gemm_bf16<0><<<dim3(2*INNER/128, LROWS/128), b256, 0, stream>>>(LMBUF, WKVT, KVL, nullptr, nullptr, LROWS, 2*INNER, DIM);

    attn_cross_part<<<dim3(BATCH, HEADS, KSPLIT), b256, 0, stream>>>(QBUF, KVX, KVL, OPART, LPART);
    attn_cross_comb<<<(32768*64)/256, b256, 0, stream>>>(OPART, LPART, AOBUF);

    gemm_bf16<2><<<dim3(DIM/128, LROWS/128), b256, 0, stream>>>(AOBUF, WOT, LAT, LAT, nullptr, LROWS, DIM, INNER);

    ln_row<u16><<<LROWS, b256, 0, stream>>>(LAT, f_n_s + l*DIM, f_n_b + l*DIM, LMBUF);
    gemm_bf16<3><<<dim3(FF/128, LROWS/128), b256, 0, stream>>>(LMBUF, W1T, HBUF, nullptr, nullptr, LROWS, FF, DIM);
    gemm_bf16<2><<<dim3(DIM/128, LROWS/128), b256, 0, stream>>>(HBUF, W2T, LAT, LAT, nullptr, LROWS, DIM, FF);
  }

  // ---- final LN -> d_out (fp32) ----
  ln_row<float><<<LROWS, b256, 0, stream>>>(LAT, out_n_s, out_n_b, (float*)d_out);
}

// Round 2
// 3671.260 us; speedup vs baseline: 1.2524x; 1.2524x over previous
//
#include <hip/hip_runtime.h>
#include <math.h>

typedef unsigned short u16;
typedef __attribute__((ext_vector_type(8))) __bf16 bf16x8;
typedef __attribute__((ext_vector_type(4))) float f32x4;
typedef __attribute__((ext_vector_type(4))) u16 u16x4;

#define DIM    2048
#define NLAT   256
#define HEADS  8
#define DHEAD  64
#define INNER  512
#define TT     24
#define NN     49
#define SEQ    (TT*NN)        // 1176
#define BATCH  16
#define MROWS  (BATCH*SEQ)    // 18816
#define LROWS  (BATCH*NLAT)   // 4096
#define KEYS   (SEQ+NLAT)     // 1432
#define KPAD   1536           // keys padded for GEMM tiling
#define FF     (DIM*4)        // 8192
#define SCALE  0.125f

__device__ __forceinline__ u16 f2bf(float f) {
  union { float f; unsigned u; } c; c.f = f;
  unsigned r = c.u + 0x7FFFu + ((c.u >> 16) & 1u);
  return (u16)(r >> 16);
}

#define AS1(p) ((__attribute__((address_space(1))) void*)(p))
#define AS3(p) ((__attribute__((address_space(3))) void*)(p))

// ---------------------------------------------------------------------------
// Weight transpose + fp32->bf16: W (K x N) -> Wt (N x K) bf16
// ---------------------------------------------------------------------------
__global__ __launch_bounds__(256) void transpose_bf16(
    const float* __restrict__ W, u16* __restrict__ Wt, int K, int N)
{
  __shared__ float tile[32][33];
  const int tx = threadIdx.x & 31, ty = threadIdx.x >> 5;   // 32 x 8
  const int n0 = blockIdx.x * 32, k0 = blockIdx.y * 32;
  #pragma unroll
  for (int p = 0; p < 4; ++p)
    tile[ty + p*8][tx] = W[(size_t)(k0 + ty + p*8) * N + n0 + tx];
  __syncthreads();
  #pragma unroll
  for (int p = 0; p < 4; ++p)
    Wt[(size_t)(n0 + ty + p*8) * K + k0 + tx] = f2bf(tile[tx][ty + p*8]);
}

// ---------------------------------------------------------------------------
// LayerNorm over rows of length DIM. OUT = u16 (bf16) or float.
// ---------------------------------------------------------------------------
template<typename OUT>
__global__ __launch_bounds__(256) void ln_row(
    const float* __restrict__ x, const float* __restrict__ s,
    const float* __restrict__ b, OUT* __restrict__ y)
{
  const size_t row = blockIdx.x;
  const int tid = threadIdx.x;
  const f32x4* xr = (const f32x4*)(x + row * DIM);
  f32x4 v0 = xr[tid], v1 = xr[tid + 256];
  float sum = v0[0]+v0[1]+v0[2]+v0[3] + v1[0]+v1[1]+v1[2]+v1[3];
  float sq  = v0[0]*v0[0]+v0[1]*v0[1]+v0[2]*v0[2]+v0[3]*v0[3]
            + v1[0]*v1[0]+v1[1]*v1[1]+v1[2]*v1[2]+v1[3]*v1[3];
  #pragma unroll
  for (int o = 32; o > 0; o >>= 1) { sum += __shfl_down(sum, o); sq += __shfl_down(sq, o); }
  __shared__ float red[18];
  const int wave = tid >> 6, lane = tid & 63;
  if (lane == 0) { red[wave] = sum; red[8 + wave] = sq; }
  __syncthreads();
  if (tid == 0) {
    float S = red[0]+red[1]+red[2]+red[3];
    float Q = red[8]+red[9]+red[10]+red[11];
    float m = S * (1.0f/DIM);
    float var = Q * (1.0f/DIM) - m*m;
    red[16] = m; red[17] = rsqrtf(var + 1e-5f);
  }
  __syncthreads();
  const float m = red[16], inv = red[17];
  const f32x4* s4 = (const f32x4*)s; const f32x4* b4 = (const f32x4*)b;
  f32x4 o0 = (v0 - m) * inv * s4[tid]       + b4[tid];
  f32x4 o1 = (v1 - m) * inv * s4[tid + 256] + b4[tid + 256];
  if (sizeof(OUT) == 2) {
    u16x4 a = {f2bf(o0[0]), f2bf(o0[1]), f2bf(o0[2]), f2bf(o0[3])};
    u16x4 c = {f2bf(o1[0]), f2bf(o1[1]), f2bf(o1[2]), f2bf(o1[3])};
    u16x4* yr = (u16x4*)((u16*)y + row * DIM);
    yr[tid] = a; yr[tid + 256] = c;
  } else {
    f32x4* yr = (f32x4*)((float*)y + row * DIM);
    yr[tid] = o0; yr[tid + 256] = o1;
  }
}

// ---------------------------------------------------------------------------
// bf16 MFMA GEMM, m97 structure: 128x128 tile, BK=32, global_load_lds w=16.
// A: M x K bf16 row-major.  Bt: N x K bf16 row-major (B transposed).
// EPI: 0 = f32 C;  1 = f32 C + seg_emb;  2 = f32 C + res;
//      3 = bf16 gelu(C);  4 = bf16 C.
// ---------------------------------------------------------------------------
template<int EPI>
__global__ __launch_bounds__(256) void gemm_bf16(
    const u16* __restrict__ A, const u16* __restrict__ Bt, void* __restrict__ Cv,
    const float* __restrict__ res, const float* __restrict__ seg,
    int M, int N, int K)
{
  __shared__ u16 lA[128 * 32];
  __shared__ u16 lB[128 * 32];
  const int tid  = threadIdx.x;
  const int wave = tid >> 6, lane = tid & 63;
  const int rowBase = blockIdx.y * 128, colBase = blockIdx.x * 128;
  const int wr = (wave >> 1) * 64, wc = (wave & 1) * 64;
  const int quad = lane >> 4, l16 = lane & 15;
  const int srow = lane >> 2, chunk = lane & 3;

  f32x4 acc[4][4] = {};

  for (int k0 = 0; k0 < K; k0 += 32) {
    #pragma unroll
    for (int c = 0; c < 2; ++c) {
      const int seg16 = wave * 2 + c;
      const int row = seg16 * 16 + srow;
      const u16* gA = A  + (size_t)(rowBase + row) * K + k0 + chunk * 8;
      const u16* gB = Bt + (size_t)(colBase + row) * K + k0 + chunk * 8;
      __builtin_amdgcn_global_load_lds(AS1(gA), AS3(&lA[seg16 * 512]), 16, 0, 0);
      __builtin_amdgcn_global_load_lds(AS1(gB), AS3(&lB[seg16 * 512]), 16, 0, 0);
    }
    __syncthreads();
    bf16x8 af[4], bf[4];
    #pragma unroll
    for (int i = 0; i < 4; ++i)
      af[i] = *(const bf16x8*)&lA[(wr + i*16 + l16) * 32 + quad * 8];
    #pragma unroll
    for (int j = 0; j < 4; ++j)
      bf[j] = *(const bf16x8*)&lB[(wc + j*16 + l16) * 32 + quad * 8];
    #pragma unroll
    for (int i = 0; i < 4; ++i)
      #pragma unroll
      for (int j = 0; j < 4; ++j)
        acc[i][j] = __builtin_amdgcn_mfma_f32_16x16x32_bf16(af[i], bf[j], acc[i][j], 0, 0, 0);
    __syncthreads();
  }

  #pragma unroll
  for (int i = 0; i < 4; ++i) {
    #pragma unroll
    for (int j = 0; j < 4; ++j) {
      const int col = colBase + wc + j*16 + l16;
      #pragma unroll
      for (int r = 0; r < 4; ++r) {
        const int row = rowBase + wr + i*16 + quad*4 + r;
        const size_t idx = (size_t)row * N + col;
        float val = acc[i][j][r];
        if (EPI == 0) {
          ((float*)Cv)[idx] = val;
        } else if (EPI == 1) {
          const int t = (row % SEQ) / NN;
          ((float*)Cv)[idx] = val + seg[t * DIM + col];
        } else if (EPI == 2) {
          ((float*)Cv)[idx] = val + res[idx];
        } else if (EPI == 3) {
          float g = 0.5f * val * (1.0f + erff(val * 0.70710678118f));
          ((u16*)Cv)[idx] = f2bf(g);
        } else {
          ((u16*)Cv)[idx] = f2bf(val);
        }
      }
    }
  }
}

// ---------------------------------------------------------------------------
// Stage-A windowed attention (unchanged from R1; fp32 VALU, 49 keys/window).
// ---------------------------------------------------------------------------
__global__ __launch_bounds__(512) void attn_local(
    const float* __restrict__ Q, const float* __restrict__ KV, u16* __restrict__ out)
{
  const int b = blockIdx.x / TT, t = blockIdx.x % TT;
  const int h = threadIdx.x >> 6, qi = threadIdx.x & 63;
  if (qi >= NN) return;
  const size_t rowq = (size_t)b * SEQ + t * NN + qi;
  const f32x4* qr = (const f32x4*)(Q + rowq * INNER + h * DHEAD);
  f32x4 qv[16];
  #pragma unroll
  for (int d = 0; d < 16; ++d) qv[d] = qr[d] * SCALE;
  f32x4 ov[16] = {};
  float l = 0.f;
  const float* kvbase = KV + ((size_t)b * SEQ + t * NN) * 1024 + h * DHEAD;
  for (int j = 0; j < NN; ++j) {
    const f32x4* kr = (const f32x4*)(kvbase + (size_t)j * 1024);
    const f32x4* vr = (const f32x4*)(kvbase + (size_t)j * 1024 + INNER);
    float s = 0.f;
    #pragma unroll
    for (int d = 0; d < 16; ++d) {
      f32x4 k4 = kr[d];
      s += qv[d][0]*k4[0] + qv[d][1]*k4[1] + qv[d][2]*k4[2] + qv[d][3]*k4[3];
    }
    float e = __expf(s);
    l += e;
    #pragma unroll
    for (int d = 0; d < 16; ++d) ov[d] += e * vr[d];
  }
  const float rl = 1.0f / l;
  u16* orow = out + rowq * INNER + h * DHEAD;
  #pragma unroll
  for (int d = 0; d < 16; ++d) {
    f32x4 o = ov[d] * rl;
    u16x4 u = {f2bf(o[0]), f2bf(o[1]), f2bf(o[2]), f2bf(o[3])};
    *(u16x4*)(orow + d * 4) = u;
  }
}

// ---------------------------------------------------------------------------
// Cross-attention scores: E[bh][i][j] = exp(SCALE * Qh[i].Kh[j]) bf16,
// keys j >= KEYS stored as 0. Per-(b,h) 256x1536 GEMM with K=64.
// Grid: (KPAD/128=12, 256/128=2, 128 bh). Block 128x128 tile, m97 structure.
// ---------------------------------------------------------------------------
__global__ __launch_bounds__(256) void egemm(
    const u16* __restrict__ QB, const u16* __restrict__ KVXB,
    const u16* __restrict__ KVLB, u16* __restrict__ E)
{
  __shared__ u16 lA[128 * 32];
  __shared__ u16 lB[128 * 32];
  const int tid = threadIdx.x;
  const int wave = tid >> 6, lane = tid & 63;
  const int quad = lane >> 4, l16 = lane & 15;
  const int srow = lane >> 2, chunk = lane & 3;
  const int ntile = blockIdx.x, mtile = blockIdx.y, bh = blockIdx.z;
  const int b = bh >> 3, h = bh & 7;
  const int wr = (wave >> 1) * 64, wc = (wave & 1) * 64;

  f32x4 acc[4][4] = {};

  for (int k0 = 0; k0 < DHEAD; k0 += 32) {
    #pragma unroll
    for (int c = 0; c < 2; ++c) {
      const int s = wave * 2 + c;
      const int r = s * 16 + srow;
      const u16* gA = QB + ((size_t)b * NLAT + mtile * 128 + r) * INNER
                         + h * DHEAD + k0 + chunk * 8;
      const int key = min(ntile * 128 + r, KEYS - 1);
      const u16* gB = (key < SEQ)
        ? KVXB + ((size_t)b * SEQ + key) * 1024 + h * DHEAD + k0 + chunk * 8
        : KVLB + ((size_t)b * NLAT + (key - SEQ)) * 1024 + h * DHEAD + k0 + chunk * 8;
      __builtin_amdgcn_global_load_lds(AS1(gA), AS3(&lA[s * 512]), 16, 0, 0);
      __builtin_amdgcn_global_load_lds(AS1(gB), AS3(&lB[s * 512]), 16, 0, 0);
    }
    __syncthreads();
    bf16x8 af[4], bfg[4];
    #pragma unroll
    for (int i = 0; i < 4; ++i)
      af[i] = *(const bf16x8*)&lA[(wr + i*16 + l16) * 32 + quad * 8];
    #pragma unroll
    for (int j = 0; j < 4; ++j)
      bfg[j] = *(const bf16x8*)&lB[(wc + j*16 + l16) * 32 + quad * 8];
    #pragma unroll
    for (int i = 0; i < 4; ++i)
      #pragma unroll
      for (int j = 0; j < 4; ++j)
        acc[i][j] = __builtin_amdgcn_mfma_f32_16x16x32_bf16(af[i], bfg[j], acc[i][j], 0, 0, 0);
    __syncthreads();
  }

  u16* Eb = E + ((size_t)bh * NLAT + mtile * 128) * KPAD;
  #pragma unroll
  for (int i = 0; i < 4; ++i) {
    #pragma unroll
    for (int j = 0; j < 4; ++j) {
      const int col = ntile * 128 + wc + j*16 + l16;
      #pragma unroll
      for (int r = 0; r < 4; ++r) {
        const int row = wr + i*16 + quad*4 + r;
        const float v = acc[i][j][r] * SCALE;
        Eb[(size_t)row * KPAD + col] = (col < KEYS) ? f2bf(__expf(v)) : (u16)0;
      }
    }
  }
}

// ---------------------------------------------------------------------------
// V transpose: VT[bh][dim 64][key KPAD] bf16, pad keys zeroed.
// Grid (KPAD/32=48, 64/32=2, 128 bh), 256 threads.
// ---------------------------------------------------------------------------
__global__ __launch_bounds__(256) void vt_build(
    const u16* __restrict__ KVXB, const u16* __restrict__ KVLB, u16* __restrict__ VT)
{
  __shared__ u16 tile[32][33];
  const int tx = threadIdx.x & 31, ty = threadIdx.x >> 5;
  const int kt = blockIdx.x, dt = blockIdx.y, bh = blockIdx.z;
  const int b = bh >> 3, h = bh & 7;
  #pragma unroll
  for (int p = 0; p < 4; ++p) {
    const int key = kt * 32 + ty + p * 8;
    const int dim = dt * 32 + tx;
    u16 v = 0;
    if (key < KEYS) {
      const u16* src = (key < SEQ)
        ? KVXB + ((size_t)b * SEQ + key) * 1024 + INNER + h * DHEAD + dim
        : KVLB + ((size_t)b * NLAT + (key - SEQ)) * 1024 + INNER + h * DHEAD + dim;
      v = *src;
    }
    tile[ty + p * 8][tx] = v;
  }
  __syncthreads();
  #pragma unroll
  for (int p = 0; p < 4; ++p) {
    const int dim = dt * 32 + ty + p * 8;
    const int key = kt * 32 + tx;
    VT[((size_t)bh * DHEAD + dim) * KPAD + key] = tile[tx][ty + p * 8];
  }
}

// ---------------------------------------------------------------------------
// O = normalize(E @ V): per block (bh, mtile): 128 queries x 64 dims, K=KPAD.
// Row-sums L fused via extra MFMA against a ones-fragment. Grid: 256 blocks.
// ---------------------------------------------------------------------------
__global__ __launch_bounds__(256) void ogemm(
    const u16* __restrict__ E, const u16* __restrict__ VT, u16* __restrict__ out)
{
  __shared__ u16 lA[128 * 32];
  __shared__ u16 lB[64 * 32];
  const int tid = threadIdx.x;
  const int wave = tid >> 6, lane = tid & 63;
  const int quad = lane >> 4, l16 = lane & 15;
  const int srow = lane >> 2, chunk = lane & 3;
  const int mtile = blockIdx.x & 1, bh = blockIdx.x >> 1;
  const int b = bh >> 3, h = bh & 7;

  const u16* Eb = E + ((size_t)bh * NLAT + mtile * 128) * KPAD;
  const u16* Vb = VT + (size_t)bh * DHEAD * KPAD;

  f32x4 acc[2][4] = {};
  f32x4 lsum[2] = {};
  bf16x8 ones;
  #pragma unroll
  for (int z = 0; z < 8; ++z) ones[z] = (__bf16)1.0f;

  for (int k0 = 0; k0 < KPAD; k0 += 32) {
    #pragma unroll
    for (int c = 0; c < 2; ++c) {
      const int s = wave * 2 + c;
      const int r = s * 16 + srow;
      const u16* gA = Eb + (size_t)r * KPAD + k0 + chunk * 8;
      __builtin_amdgcn_global_load_lds(AS1(gA), AS3(&lA[s * 512]), 16, 0, 0);
    }
    {
      const int r = wave * 16 + srow;   // dim row 0..63
      const u16* gB = Vb + (size_t)r * KPAD + k0 + chunk * 8;
      __builtin_amdgcn_global_load_lds(AS1(gB), AS3(&lB[wave * 512]), 16, 0, 0);
    }
    __syncthreads();
    bf16x8 af[2], bfg[4];
    #pragma unroll
    for (int i = 0; i < 2; ++i)
      af[i] = *(const bf16x8*)&lA[(wave*32 + i*16 + l16) * 32 + quad * 8];
    #pragma unroll
    for (int j = 0; j < 4; ++j)
      bfg[j] = *(const bf16x8*)&lB[(j*16 + l16) * 32 + quad * 8];
    #pragma unroll
    for (int i = 0; i < 2; ++i) {
      lsum[i] = __builtin_amdgcn_mfma_f32_16x16x32_bf16(af[i], ones, lsum[i], 0, 0, 0);
      #pragma unroll
      for (int j = 0; j < 4; ++j)
        acc[i][j] = __builtin_amdgcn_mfma_f32_16x16x32_bf16(af[i], bfg[j], acc[i][j], 0, 0, 0);
    }
    __syncthreads();
  }

  #pragma unroll
  for (int i = 0; i < 2; ++i) {
    #pragma unroll
    for (int r = 0; r < 4; ++r) {
      const int row = mtile * 128 + wave * 32 + i * 16 + quad * 4 + r;
      const float rl = 1.0f / lsum[i][r];
      #pragma unroll
      for (int j = 0; j < 4; ++j) {
        const int col = j * 16 + l16;
        out[((size_t)b * NLAT + row) * INNER + h * DHEAD + col] = f2bf(acc[i][j][r] * rl);
      }
    }
  }
}

// ---------------------------------------------------------------------------
// lat init: lat[b*256+i][:] = latents[i][:]
// ---------------------------------------------------------------------------
__global__ __launch_bounds__(256) void lat_init(
    const float* __restrict__ latents, float* __restrict__ lat)
{
  const size_t i = (size_t)blockIdx.x * 256 + threadIdx.x;  // f32x4 units
  const size_t row = i >> 9, c4 = i & 511;
  ((f32x4*)lat)[i] = ((const f32x4*)latents)[(row & (NLAT - 1)) * 512 + c4];
}

// ---------------------------------------------------------------------------
// Launcher.
// ---------------------------------------------------------------------------
extern "C" void kernel_launch(void* const* d_in, const int* in_sizes, int n_in,
                              void* d_out, int out_size, void* d_ws, size_t ws_size,
                              hipStream_t stream) {
  const float* x        = (const float*)d_in[0];
  const float* g_norm_s = (const float*)d_in[1];
  const float* g_norm_b = (const float*)d_in[2];
  const float* g_wq     = (const float*)d_in[3];
  const float* g_wkv    = (const float*)d_in[4];
  const float* g_wo     = (const float*)d_in[5];
  const float* seg_emb  = (const float*)d_in[6];
  const float* latents  = (const float*)d_in[7];
  const float* a_nm_s   = (const float*)d_in[8];
  const float* a_nm_b   = (const float*)d_in[9];
  const float* a_nl_s   = (const float*)d_in[10];
  const float* a_nl_b   = (const float*)d_in[11];
  const float* a_wq     = (const float*)d_in[12];
  const float* a_wkv    = (const float*)d_in[13];
  const float* a_wo     = (const float*)d_in[14];
  const float* f_n_s    = (const float*)d_in[15];
  const float* f_n_b    = (const float*)d_in[16];
  const float* f_w1     = (const float*)d_in[17];
  const float* f_w2     = (const float*)d_in[18];
  const float* out_n_s  = (const float*)d_in[19];
  const float* out_n_b  = (const float*)d_in[20];

  size_t off = 0;
  auto alloc = [&](size_t bytes) -> char* {
    char* p = (char*)d_ws + off;
    off += (bytes + 255) & ~(size_t)255;
    return p;
  };
  float* XBUF  = (float*)alloc((size_t)MROWS * DIM * 4);
  u16*   TBUF  = (u16*)  alloc((size_t)MROWS * DIM * 2);
  u16*   LMBUF = (u16*)  alloc((size_t)LROWS * DIM * 2);
  float* LAT   = (float*)alloc((size_t)LROWS * DIM * 4);
  u16*   AOBUF = (u16*)  alloc((size_t)MROWS * INNER * 2);
  u16*   WT    = (u16*)  alloc((size_t)37748736 * 2);
  u16*   HBUF  = (u16*)  alloc((size_t)LROWS * FF * 2);
  // Union region: stage A fp32 Q/KV  vs  layer-phase bf16 attn buffers.
  char*  U     = alloc((size_t)MROWS * INNER * 4 + (size_t)MROWS * 2 * INNER * 4); // 192.7 MB
  (void)ws_size; (void)n_in; (void)in_sizes; (void)out_size;

  // stage A views
  float* QBUF = (float*)U;                                       // 38.5 MB
  float* KVX  = (float*)(U + (size_t)MROWS * INNER * 4);         // 154.1 MB
  // layer-phase views
  u16* EBUF  = (u16*)U;                                          // 100.7 MB
  u16* VT    = (u16*)(U + (size_t)128 * NLAT * KPAD * 2);        // 25.2 MB
  u16* QB    = (u16*)(U + (size_t)128 * NLAT * KPAD * 2 + (size_t)128 * DHEAD * KPAD * 2);
  u16* KVXB  = (u16*)((char*)QB + (size_t)LROWS * INNER * 2);    // 38.5 MB
  u16* KVLB  = (u16*)((char*)KVXB + (size_t)MROWS * 2 * INNER * 2); // 8.4 MB

  u16* WQT  = WT;                       // 512  x 2048
  u16* WKVT = WT + 1048576;             // 1024 x 2048
  u16* WOT  = WT + 3145728;             // 2048 x 512
  u16* W1T  = WT + 4194304;             // 8192 x 2048
  u16* W2T  = WT + 20971520;            // 2048 x 8192

  const dim3 b256(256);

  // ---- Stage A ----
  transpose_bf16<<<dim3(INNER/32, DIM/32), b256, 0, stream>>>(g_wq,  WQT,  DIM, INNER);
  transpose_bf16<<<dim3(2*INNER/32, DIM/32), b256, 0, stream>>>(g_wkv, WKVT, DIM, 2*INNER);
  transpose_bf16<<<dim3(DIM/32, INNER/32), b256, 0, stream>>>(g_wo,  WOT,  INNER, DIM);
  ln_row<u16><<<MROWS, b256, 0, stream>>>(x, g_norm_s, g_norm_b, TBUF);
  gemm_bf16<0><<<dim3(INNER/128, MROWS/128), b256, 0, stream>>>(TBUF, WQT, QBUF, nullptr, nullptr, MROWS, INNER, DIM);
  gemm_bf16<0><<<dim3(2*INNER/128, MROWS/128), b256, 0, stream>>>(TBUF, WKVT, KVX, nullptr, nullptr, MROWS, 2*INNER, DIM);
  attn_local<<<BATCH*TT, dim3(512), 0, stream>>>(QBUF, KVX, AOBUF);
  gemm_bf16<1><<<dim3(DIM/128, MROWS/128), b256, 0, stream>>>(AOBUF, WOT, XBUF, nullptr, seg_emb, MROWS, DIM, INNER);
  lat_init<<<(LROWS*DIM/4)/256, b256, 0, stream>>>(latents, LAT);

  // ---- DEPTH layers ----
  for (int l = 0; l < 3; ++l) {
    transpose_bf16<<<dim3(INNER/32, DIM/32), b256, 0, stream>>>(a_wq + (size_t)l*DIM*INNER, WQT, DIM, INNER);
    transpose_bf16<<<dim3(2*INNER/32, DIM/32), b256, 0, stream>>>(a_wkv + (size_t)l*DIM*2*INNER, WKVT, DIM, 2*INNER);
    transpose_bf16<<<dim3(DIM/32, INNER/32), b256, 0, stream>>>(a_wo + (size_t)l*INNER*DIM, WOT, INNER, DIM);
    transpose_bf16<<<dim3(FF/32, DIM/32), b256, 0, stream>>>(f_w1 + (size_t)l*DIM*FF, W1T, DIM, FF);
    transpose_bf16<<<dim3(DIM/32, FF/32), b256, 0, stream>>>(f_w2 + (size_t)l*FF*DIM, W2T, FF, DIM);

    ln_row<u16><<<MROWS, b256, 0, stream>>>(XBUF, a_nm_s + l*DIM, a_nm_b + l*DIM, TBUF);
    ln_row<u16><<<LROWS, b256, 0, stream>>>(LAT, a_nl_s + l*DIM, a_nl_b + l*DIM, LMBUF);

    gemm_bf16<4><<<dim3(INNER/128, LROWS/128), b256, 0, stream>>>(LMBUF, WQT, QB, nullptr, nullptr, LROWS, INNER, DIM);
    gemm_bf16<4><<<dim3(2*INNER/128, MROWS/128), b256, 0, stream>>>(TBUF, WKVT, KVXB, nullptr, nullptr, MROWS, 2*INNER, DIM);
    gemm_bf16<4><<<dim3(2*INNER/128, LROWS/128), b256, 0, stream>>>(LMBUF, WKVT, KVLB, nullptr, nullptr, LROWS, 2*INNER, DIM);

    vt_build<<<dim3(KPAD/32, 2, 128), b256, 0, stream>>>(KVXB, KVLB, VT);
    egemm<<<dim3(KPAD/128, 2, 128), b256, 0, stream>>>(QB, KVXB, KVLB, EBUF);
    ogemm<<<dim3(256), b256, 0, stream>>>(EBUF, VT, AOBUF);

    gemm_bf16<2><<<dim3(DIM/128, LROWS/128), b256, 0, stream>>>(AOBUF, WOT, LAT, LAT, nullptr, LROWS, DIM, INNER);

    ln_row<u16><<<LROWS, b256, 0, stream>>>(LAT, f_n_s + l*DIM, f_n_b + l*DIM, LMBUF);
    gemm_bf16<3><<<dim3(FF/128, LROWS/128), b256, 0, stream>>>(LMBUF, W1T, HBUF, nullptr, nullptr, LROWS, FF, DIM);
    gemm_bf16<2><<<dim3(DIM/128, LROWS/128), b256, 0, stream>>>(HBUF, W2T, LAT, LAT, nullptr, LROWS, DIM, FF);
  }

  ln_row<float><<<LROWS, b256, 0, stream>>>(LAT, out_n_s, out_n_b, (float*)d_out);
}

// Round 3
// 3347.345 us; speedup vs baseline: 1.3736x; 1.0968x over previous
//
#include <hip/hip_runtime.h>
#include <math.h>

typedef unsigned short u16;
typedef __attribute__((ext_vector_type(8))) __bf16 bf16x8;
typedef __attribute__((ext_vector_type(4))) float f32x4;
typedef __attribute__((ext_vector_type(4))) u16 u16x4;

#define DIM    2048
#define NLAT   256
#define HEADS  8
#define DHEAD  64
#define INNER  512
#define TT     24
#define NN     49
#define SEQ    (TT*NN)        // 1176
#define BATCH  16
#define MROWS  (BATCH*SEQ)    // 18816
#define LROWS  (BATCH*NLAT)   // 4096
#define KEYS   (SEQ+NLAT)     // 1432
#define KPAD   1536
#define FF     (DIM*4)        // 8192
#define SCALE  0.125f

__device__ __forceinline__ u16 f2bf(float f) {
  union { float f; unsigned u; } c; c.f = f;
  unsigned r = c.u + 0x7FFFu + ((c.u >> 16) & 1u);
  return (u16)(r >> 16);
}

#define AS1(p) ((__attribute__((address_space(1))) void*)(p))
#define AS3(p) ((__attribute__((address_space(3))) void*)(p))

// ---------------------------------------------------------------------------
// Weight transpose + fp32->bf16: W (K x N) -> Wt (N x K) bf16
// ---------------------------------------------------------------------------
__global__ __launch_bounds__(256) void transpose_bf16(
    const float* __restrict__ W, u16* __restrict__ Wt, int K, int N)
{
  __shared__ float tile[32][33];
  const int tx = threadIdx.x & 31, ty = threadIdx.x >> 5;   // 32 x 8
  const int n0 = blockIdx.x * 32, k0 = blockIdx.y * 32;
  #pragma unroll
  for (int p = 0; p < 4; ++p)
    tile[ty + p*8][tx] = W[(size_t)(k0 + ty + p*8) * N + n0 + tx];
  __syncthreads();
  #pragma unroll
  for (int p = 0; p < 4; ++p)
    Wt[(size_t)(n0 + ty + p*8) * K + k0 + tx] = f2bf(tile[tx][ty + p*8]);
}

// ---------------------------------------------------------------------------
// LayerNorm over rows of length DIM. OUT = u16 (bf16) or float.
// ---------------------------------------------------------------------------
template<typename OUT>
__global__ __launch_bounds__(256) void ln_row(
    const float* __restrict__ x, const float* __restrict__ s,
    const float* __restrict__ b, OUT* __restrict__ y)
{
  const size_t row = blockIdx.x;
  const int tid = threadIdx.x;
  const f32x4* xr = (const f32x4*)(x + row * DIM);
  f32x4 v0 = xr[tid], v1 = xr[tid + 256];
  float sum = v0[0]+v0[1]+v0[2]+v0[3] + v1[0]+v1[1]+v1[2]+v1[3];
  float sq  = v0[0]*v0[0]+v0[1]*v0[1]+v0[2]*v0[2]+v0[3]*v0[3]
            + v1[0]*v1[0]+v1[1]*v1[1]+v1[2]*v1[2]+v1[3]*v1[3];
  #pragma unroll
  for (int o = 32; o > 0; o >>= 1) { sum += __shfl_down(sum, o); sq += __shfl_down(sq, o); }
  __shared__ float red[18];
  const int wave = tid >> 6, lane = tid & 63;
  if (lane == 0) { red[wave] = sum; red[8 + wave] = sq; }
  __syncthreads();
  if (tid == 0) {
    float S = red[0]+red[1]+red[2]+red[3];
    float Q = red[8]+red[9]+red[10]+red[11];
    float m = S * (1.0f/DIM);
    float var = Q * (1.0f/DIM) - m*m;
    red[16] = m; red[17] = rsqrtf(var + 1e-5f);
  }
  __syncthreads();
  const float m = red[16], inv = red[17];
  const f32x4* s4 = (const f32x4*)s; const f32x4* b4 = (const f32x4*)b;
  f32x4 o0 = (v0 - m) * inv * s4[tid]       + b4[tid];
  f32x4 o1 = (v1 - m) * inv * s4[tid + 256] + b4[tid + 256];
  if (sizeof(OUT) == 2) {
    u16x4 a = {f2bf(o0[0]), f2bf(o0[1]), f2bf(o0[2]), f2bf(o0[3])};
    u16x4 c = {f2bf(o1[0]), f2bf(o1[1]), f2bf(o1[2]), f2bf(o1[3])};
    u16x4* yr = (u16x4*)((u16*)y + row * DIM);
    yr[tid] = a; yr[tid + 256] = c;
  } else {
    f32x4* yr = (f32x4*)((float*)y + row * DIM);
    yr[tid] = o0; yr[tid + 256] = o1;
  }
}

// ---------------------------------------------------------------------------
// bf16 MFMA GEMM, BK=64, XCD-aware swizzle, XOR-permuted LDS chunks.
// A: M x lda bf16 (use K cols from koff).  Bt: N x ldb bf16.
// EPI: 0=f32 C; 1=f32 C+seg; 2=f32 C+res; 3=bf16 gelu(C); 4=bf16 C;
//      5=f32 partial to Cv + z*M*N (split-K via blockIdx.z).
// Launch: gridDim.y padded so gridDim.x*gridDim.y % 8 == 0.
// ---------------------------------------------------------------------------
template<int EPI>
__global__ __launch_bounds__(256) void gemm64(
    const u16* __restrict__ A, const u16* __restrict__ Bt, void* __restrict__ Cv,
    const float* __restrict__ res, const float* __restrict__ seg,
    int M, int N, int Klen, int lda, int ldb)
{
  __shared__ u16 lA[128 * 64];
  __shared__ u16 lB[128 * 64];
  const int tid  = threadIdx.x;
  const int wave = tid >> 6, lane = tid & 63;
  const int quad = lane >> 4, l16 = lane & 15;
  const int srow = lane >> 3, chunk = lane & 7;
  const int pchunk = chunk ^ srow;              // XOR bank spread

  // XCD-aware swizzle: id%8 = XCD (round-robin); same-XCD consecutive ids
  // walk column tiles innermost over a contiguous row range -> A L2 reuse.
  const int nx = gridDim.x;
  const int ny = M >> 7;
  const int id = blockIdx.y * nx + blockIdx.x;
  const int nseq = (nx * gridDim.y) >> 3;
  const int W = (id & 7) * nseq + (id >> 3);
  const int row_t = W / nx, col_t = W - row_t * nx;
  if (row_t >= ny) return;
  const int rowBase = row_t * 128, colBase = col_t * 128;
  const int wr = (wave >> 1) * 64, wc = (wave & 1) * 64;
  const int koff = (EPI == 5) ? blockIdx.z * Klen : 0;

  f32x4 acc[4][4] = {};

  for (int k0 = 0; k0 < Klen; k0 += 64) {
    #pragma unroll
    for (int i = 0; i < 4; ++i) {
      const int seg8 = wave * 4 + i;            // 0..15, wave-uniform
      const int row = seg8 * 8 + srow;
      const u16* gA = A  + (size_t)(rowBase + row) * lda + koff + k0 + pchunk * 8;
      const u16* gB = Bt + (size_t)(colBase + row) * ldb + koff + k0 + pchunk * 8;
      __builtin_amdgcn_global_load_lds(AS1(gA), AS3(&lA[seg8 * 512]), 16, 0, 0);
      __builtin_amdgcn_global_load_lds(AS1(gB), AS3(&lB[seg8 * 512]), 16, 0, 0);
    }
    __syncthreads();
    #pragma unroll
    for (int t = 0; t < 2; ++t) {
      bf16x8 af[4], bfr[4];
      #pragma unroll
      for (int i = 0; i < 4; ++i) {
        const int row = wr + i*16 + l16;
        af[i] = *(const bf16x8*)&lA[row*64 + (((t*4 + quad) ^ (row & 7)) * 8)];
      }
      #pragma unroll
      for (int j = 0; j < 4; ++j) {
        const int row = wc + j*16 + l16;
        bfr[j] = *(const bf16x8*)&lB[row*64 + (((t*4 + quad) ^ (row & 7)) * 8)];
      }
      #pragma unroll
      for (int i = 0; i < 4; ++i)
        #pragma unroll
        for (int j = 0; j < 4; ++j)
          acc[i][j] = __builtin_amdgcn_mfma_f32_16x16x32_bf16(af[i], bfr[j], acc[i][j], 0, 0, 0);
    }
    __syncthreads();
  }

  float* Pc = (EPI == 5) ? (float*)Cv + (size_t)blockIdx.z * ((size_t)M * N) : (float*)Cv;
  #pragma unroll
  for (int i = 0; i < 4; ++i) {
    #pragma unroll
    for (int j = 0; j < 4; ++j) {
      const int col = colBase + wc + j*16 + l16;
      #pragma unroll
      for (int r = 0; r < 4; ++r) {
        const int row = rowBase + wr + i*16 + quad*4 + r;
        const size_t idx = (size_t)row * N + col;
        float val = acc[i][j][r];
        if (EPI == 0) {
          Pc[idx] = val;
        } else if (EPI == 1) {
          const int t = (row % SEQ) / NN;
          Pc[idx] = val + seg[t * DIM + col];
        } else if (EPI == 2) {
          Pc[idx] = val + res[idx];
        } else if (EPI == 3) {
          float g = 0.5f * val * (1.0f + erff(val * 0.70710678118f));
          ((u16*)Cv)[idx] = f2bf(g);
        } else if (EPI == 4) {
          ((u16*)Cv)[idx] = f2bf(val);
        } else {
          Pc[idx] = val;
        }
      }
    }
  }
}

// ---------------------------------------------------------------------------
// ffn2 split-K combine: LAT += P[0] + P[1]
// ---------------------------------------------------------------------------
__global__ __launch_bounds__(256) void combine_ffn(
    const float* __restrict__ P, float* __restrict__ LAT)
{
  const size_t i = (size_t)blockIdx.x * 256 + threadIdx.x;   // f32x4 units
  f32x4 a = ((const f32x4*)P)[i];
  f32x4 b = ((const f32x4*)(P + (size_t)LROWS * DIM))[i];
  ((f32x4*)LAT)[i] = ((f32x4*)LAT)[i] + a + b;
}

// ---------------------------------------------------------------------------
// Stage-A windowed attention on fused QKV fp32 (row stride 1536:
// q at +0, k at +512, v at +1024).
// ---------------------------------------------------------------------------
__global__ __launch_bounds__(512) void attn_local(
    const float* __restrict__ QKV, u16* __restrict__ out)
{
  const int b = blockIdx.x / TT, t = blockIdx.x % TT;
  const int h = threadIdx.x >> 6, qi = threadIdx.x & 63;
  if (qi >= NN) return;
  const size_t rowq = (size_t)b * SEQ + t * NN + qi;
  const f32x4* qr = (const f32x4*)(QKV + rowq * 1536 + h * DHEAD);
  f32x4 qv[16];
  #pragma unroll
  for (int d = 0; d < 16; ++d) qv[d] = qr[d] * SCALE;
  f32x4 ov[16] = {};
  float l = 0.f;
  const float* kvbase = QKV + ((size_t)b * SEQ + t * NN) * 1536 + h * DHEAD;
  for (int j = 0; j < NN; ++j) {
    const f32x4* kr = (const f32x4*)(kvbase + (size_t)j * 1536 + 512);
    const f32x4* vr = (const f32x4*)(kvbase + (size_t)j * 1536 + 1024);
    float s = 0.f;
    #pragma unroll
    for (int d = 0; d < 16; ++d) {
      f32x4 k4 = kr[d];
      s += qv[d][0]*k4[0] + qv[d][1]*k4[1] + qv[d][2]*k4[2] + qv[d][3]*k4[3];
    }
    float e = __expf(s);
    l += e;
    #pragma unroll
    for (int d = 0; d < 16; ++d) ov[d] += e * vr[d];
  }
  const float rl = 1.0f / l;
  u16* orow = out + rowq * INNER + h * DHEAD;
  #pragma unroll
  for (int d = 0; d < 16; ++d) {
    f32x4 o = ov[d] * rl;
    u16x4 u = {f2bf(o[0]), f2bf(o[1]), f2bf(o[2]), f2bf(o[3])};
    *(u16x4*)(orow + d * 4) = u;
  }
}

// ---------------------------------------------------------------------------
// Cross-attn scores: E[bh][i][j] = exp(SCALE * q_i . k_j) bf16, pad keys = 0.
// Q from fused QKVL (stride 1536, q at +0, k at +512); x-keys from KVXB
// (stride 1024, k at +0).
// ---------------------------------------------------------------------------
__global__ __launch_bounds__(256) void egemm(
    const u16* __restrict__ QKVL, const u16* __restrict__ KVXB, u16* __restrict__ E)
{
  __shared__ u16 lA[128 * 32];
  __shared__ u16 lB[128 * 32];
  const int tid = threadIdx.x;
  const int wave = tid >> 6, lane = tid & 63;
  const int quad = lane >> 4, l16 = lane & 15;
  const int srow = lane >> 2, chunk = lane & 3;
  const int ntile = blockIdx.x, mtile = blockIdx.y, bh = blockIdx.z;
  const int b = bh >> 3, h = bh & 7;
  const int wr = (wave >> 1) * 64, wc = (wave & 1) * 64;

  f32x4 acc[4][4] = {};

  for (int k0 = 0; k0 < DHEAD; k0 += 32) {
    #pragma unroll
    for (int c = 0; c < 2; ++c) {
      const int s = wave * 2 + c;
      const int r = s * 16 + srow;
      const u16* gA = QKVL + ((size_t)b * NLAT + mtile * 128 + r) * 1536
                           + h * DHEAD + k0 + chunk * 8;
      const int key = min(ntile * 128 + r, KEYS - 1);
      const u16* gB = (key < SEQ)
        ? KVXB + ((size_t)b * SEQ + key) * 1024 + h * DHEAD + k0 + chunk * 8
        : QKVL + ((size_t)b * NLAT + (key - SEQ)) * 1536 + 512 + h * DHEAD + k0 + chunk * 8;
      __builtin_amdgcn_global_load_lds(AS1(gA), AS3(&lA[s * 512]), 16, 0, 0);
      __builtin_amdgcn_global_load_lds(AS1(gB), AS3(&lB[s * 512]), 16, 0, 0);
    }
    __syncthreads();
    bf16x8 af[4], bfg[4];
    #pragma unroll
    for (int i = 0; i < 4; ++i)
      af[i] = *(const bf16x8*)&lA[(wr + i*16 + l16) * 32 + quad * 8];
    #pragma unroll
    for (int j = 0; j < 4; ++j)
      bfg[j] = *(const bf16x8*)&lB[(wc + j*16 + l16) * 32 + quad * 8];
    #pragma unroll
    for (int i = 0; i < 4; ++i)
      #pragma unroll
      for (int j = 0; j < 4; ++j)
        acc[i][j] = __builtin_amdgcn_mfma_f32_16x16x32_bf16(af[i], bfg[j], acc[i][j], 0, 0, 0);
    __syncthreads();
  }

  u16* Eb = E + ((size_t)bh * NLAT + mtile * 128) * KPAD;
  #pragma unroll
  for (int i = 0; i < 4; ++i) {
    #pragma unroll
    for (int j = 0; j < 4; ++j) {
      const int col = ntile * 128 + wc + j*16 + l16;
      #pragma unroll
      for (int r = 0; r < 4; ++r) {
        const int row = wr + i*16 + quad*4 + r;
        const float v = acc[i][j][r] * SCALE;
        Eb[(size_t)row * KPAD + col] = (col < KEYS) ? f2bf(__expf(v)) : (u16)0;
      }
    }
  }
}

// ---------------------------------------------------------------------------
// V transpose: VT[bh][64][KPAD] bf16, pad keys zeroed. V from KVXB (+512) /
// QKVL (+1024).
// ---------------------------------------------------------------------------
__global__ __launch_bounds__(256) void vt_build(
    const u16* __restrict__ KVXB, const u16* __restrict__ QKVL, u16* __restrict__ VT)
{
  __shared__ u16 tile[32][33];
  const int tx = threadIdx.x & 31, ty = threadIdx.x >> 5;
  const int kt = blockIdx.x, dt = blockIdx.y, bh = blockIdx.z;
  const int b = bh >> 3, h = bh & 7;
  #pragma unroll
  for (int p = 0; p < 4; ++p) {
    const int key = kt * 32 + ty + p * 8;
    const int dim = dt * 32 + tx;
    u16 v = 0;
    if (key < KEYS) {
      const u16* src = (key < SEQ)
        ? KVXB + ((size_t)b * SEQ + key) * 1024 + 512 + h * DHEAD + dim
        : QKVL + ((size_t)b * NLAT + (key - SEQ)) * 1536 + 1024 + h * DHEAD + dim;
      v = *src;
    }
    tile[ty + p * 8][tx] = v;
  }
  __syncthreads();
  #pragma unroll
  for (int p = 0; p < 4; ++p) {
    const int dim = dt * 32 + ty + p * 8;
    const int key = kt * 32 + tx;
    VT[((size_t)bh * DHEAD + dim) * KPAD + key] = tile[tx][ty + p * 8];
  }
}

// ---------------------------------------------------------------------------
// O = normalize(E @ V), row-sums via ones-fragment MFMA. Grid: 256 blocks.
// ---------------------------------------------------------------------------
__global__ __launch_bounds__(256) void ogemm(
    const u16* __restrict__ E, const u16* __restrict__ VT, u16* __restrict__ out)
{
  __shared__ u16 lA[128 * 32];
  __shared__ u16 lB[64 * 32];
  const int tid = threadIdx.x;
  const int wave = tid >> 6, lane = tid & 63;
  const int quad = lane >> 4, l16 = lane & 15;
  const int srow = lane >> 2, chunk = lane & 3;
  const int mtile = blockIdx.x & 1, bh = blockIdx.x >> 1;
  const int b = bh >> 3, h = bh & 7;

  const u16* Eb = E + ((size_t)bh * NLAT + mtile * 128) * KPAD;
  const u16* Vb = VT + (size_t)bh * DHEAD * KPAD;

  f32x4 acc[2][4] = {};
  f32x4 lsum[2] = {};
  bf16x8 ones;
  #pragma unroll
  for (int z = 0; z < 8; ++z) ones[z] = (__bf16)1.0f;

  for (int k0 = 0; k0 < KPAD; k0 += 32) {
    #pragma unroll
    for (int c = 0; c < 2; ++c) {
      const int s = wave * 2 + c;
      const int r = s * 16 + srow;
      __builtin_amdgcn_global_load_lds(AS1(Eb + (size_t)r * KPAD + k0 + chunk * 8),
                                       AS3(&lA[s * 512]), 16, 0, 0);
    }
    {
      const int r = wave * 16 + srow;
      __builtin_amdgcn_global_load_lds(AS1(Vb + (size_t)r * KPAD + k0 + chunk * 8),
                                       AS3(&lB[wave * 512]), 16, 0, 0);
    }
    __syncthreads();
    bf16x8 af[2], bfg[4];
    #pragma unroll
    for (int i = 0; i < 2; ++i)
      af[i] = *(const bf16x8*)&lA[(wave*32 + i*16 + l16) * 32 + quad * 8];
    #pragma unroll
    for (int j = 0; j < 4; ++j)
      bfg[j] = *(const bf16x8*)&lB[(j*16 + l16) * 32 + quad * 8];
    #pragma unroll
    for (int i = 0; i < 2; ++i) {
      lsum[i] = __builtin_amdgcn_mfma_f32_16x16x32_bf16(af[i], ones, lsum[i], 0, 0, 0);
      #pragma unroll
      for (int j = 0; j < 4; ++j)
        acc[i][j] = __builtin_amdgcn_mfma_f32_16x16x32_bf16(af[i], bfg[j], acc[i][j], 0, 0, 0);
    }
    __syncthreads();
  }

  #pragma unroll
  for (int i = 0; i < 2; ++i) {
    #pragma unroll
    for (int r = 0; r < 4; ++r) {
      const int row = mtile * 128 + wave * 32 + i * 16 + quad * 4 + r;
      const float rl = 1.0f / lsum[i][r];
      #pragma unroll
      for (int j = 0; j < 4; ++j) {
        const int col = j * 16 + l16;
        out[((size_t)b * NLAT + row) * INNER + h * DHEAD + col] = f2bf(acc[i][j][r] * rl);
      }
    }
  }
}

__global__ __launch_bounds__(256) void lat_init(
    const float* __restrict__ latents, float* __restrict__ lat)
{
  const size_t i = (size_t)blockIdx.x * 256 + threadIdx.x;  // f32x4 units
  const size_t row = i >> 9, c4 = i & 511;
  ((f32x4*)lat)[i] = ((const f32x4*)latents)[(row & (NLAT - 1)) * 512 + c4];
}

// ---------------------------------------------------------------------------
// Launcher.
// ---------------------------------------------------------------------------
extern "C" void kernel_launch(void* const* d_in, const int* in_sizes, int n_in,
                              void* d_out, int out_size, void* d_ws, size_t ws_size,
                              hipStream_t stream) {
  const float* x        = (const float*)d_in[0];
  const float* g_norm_s = (const float*)d_in[1];
  const float* g_norm_b = (const float*)d_in[2];
  const float* g_wq     = (const float*)d_in[3];
  const float* g_wkv    = (const float*)d_in[4];
  const float* g_wo     = (const float*)d_in[5];
  const float* seg_emb  = (const float*)d_in[6];
  const float* latents  = (const float*)d_in[7];
  const float* a_nm_s   = (const float*)d_in[8];
  const float* a_nm_b   = (const float*)d_in[9];
  const float* a_nl_s   = (const float*)d_in[10];
  const float* a_nl_b   = (const float*)d_in[11];
  const float* a_wq     = (const float*)d_in[12];
  const float* a_wkv    = (const float*)d_in[13];
  const float* a_wo     = (const float*)d_in[14];
  const float* f_n_s    = (const float*)d_in[15];
  const float* f_n_b    = (const float*)d_in[16];
  const float* f_w1     = (const float*)d_in[17];
  const float* f_w2     = (const float*)d_in[18];
  const float* out_n_s  = (const float*)d_in[19];
  const float* out_n_b  = (const float*)d_in[20];

  size_t off = 0;
  auto alloc = [&](size_t bytes) -> char* {
    char* p = (char*)d_ws + off;
    off += (bytes + 255) & ~(size_t)255;
    return p;
  };
  float* XBUF  = (float*)alloc((size_t)MROWS * DIM * 4);      // 154.1 MB
  u16*   TBUF  = (u16*)  alloc((size_t)MROWS * DIM * 2);      // 77.1 MB
  u16*   LMBUF = (u16*)  alloc((size_t)LROWS * DIM * 2);      // 16.8 MB
  float* LAT   = (float*)alloc((size_t)LROWS * DIM * 4);      // 33.6 MB
  u16*   AOBUF = (u16*)  alloc((size_t)MROWS * INNER * 2);    // 19.3 MB
  u16*   WT    = (u16*)  alloc((size_t)37748736 * 2);         // 75.5 MB
  u16*   HBUF  = (u16*)  alloc((size_t)LROWS * FF * 2);       // 67.1 MB
  char*  U     = alloc((size_t)178000000);                    // union region
  (void)ws_size; (void)n_in; (void)in_sizes; (void)out_size;

  // stage A view: fused QKV fp32 (18816 x 1536) = 115.6 MB
  float* QKV = (float*)U;
  // layer-phase views
  u16* EBUF  = (u16*)U;                                           // 100.7 MB
  float* PART = (float*)U;                                        // 67.1 MB (after ogemm)
  u16* VT    = (u16*)(U + (size_t)128 * NLAT * KPAD * 2);         // 25.2 MB
  u16* QKVL  = (u16*)(U + (size_t)128 * NLAT * KPAD * 2 + (size_t)128 * DHEAD * KPAD * 2);
  u16* KVXB  = (u16*)((char*)QKVL + (size_t)LROWS * 1536 * 2);    // 38.5 MB

  u16* Wcat = WT;                       // 1536 x 2048 (q rows 0-511, kv 512-1535)
  u16* WKVT = WT + (size_t)512 * 2048;  // alias: kv part of Wcat
  u16* WOT  = WT + 3145728;             // 2048 x 512
  u16* W1T  = WT + 4194304;             // 8192 x 2048
  u16* W2T  = WT + 20971520;            // 2048 x 8192

  const dim3 b256(256);
  auto ypad = [](int nx, int ny) { while ((nx * ny) & 7) ny++; return ny; };

  // ---- Stage A ----
  transpose_bf16<<<dim3(INNER/32, DIM/32), b256, 0, stream>>>(g_wq,  Wcat, DIM, INNER);
  transpose_bf16<<<dim3(2*INNER/32, DIM/32), b256, 0, stream>>>(g_wkv, WKVT, DIM, 2*INNER);
  transpose_bf16<<<dim3(DIM/32, INNER/32), b256, 0, stream>>>(g_wo,  WOT,  INNER, DIM);
  ln_row<u16><<<MROWS, b256, 0, stream>>>(x, g_norm_s, g_norm_b, TBUF);
  gemm64<0><<<dim3(12, ypad(12, 147)), b256, 0, stream>>>(TBUF, Wcat, QKV, nullptr, nullptr, MROWS, 1536, DIM, DIM, DIM);
  attn_local<<<BATCH*TT, dim3(512), 0, stream>>>(QKV, AOBUF);
  gemm64<1><<<dim3(16, 147), b256, 0, stream>>>(AOBUF, WOT, XBUF, nullptr, seg_emb, MROWS, DIM, INNER, INNER, INNER);
  lat_init<<<(LROWS*DIM/4)/256, b256, 0, stream>>>(latents, LAT);

  // ---- DEPTH layers ----
  for (int l = 0; l < 3; ++l) {
    transpose_bf16<<<dim3(INNER/32, DIM/32), b256, 0, stream>>>(a_wq + (size_t)l*DIM*INNER, Wcat, DIM, INNER);
    transpose_bf16<<<dim3(2*INNER/32, DIM/32), b256, 0, stream>>>(a_wkv + (size_t)l*DIM*2*INNER, WKVT, DIM, 2*INNER);
    transpose_bf16<<<dim3(DIM/32, INNER/32), b256, 0, stream>>>(a_wo + (size_t)l*INNER*DIM, WOT, INNER, DIM);
    transpose_bf16<<<dim3(FF/32, DIM/32), b256, 0, stream>>>(f_w1 + (size_t)l*DIM*FF, W1T, DIM, FF);
    transpose_bf16<<<dim3(DIM/32, FF/32), b256, 0, stream>>>(f_w2 + (size_t)l*FF*DIM, W2T, FF, DIM);

    ln_row<u16><<<MROWS, b256, 0, stream>>>(XBUF, a_nm_s + l*DIM, a_nm_b + l*DIM, TBUF);
    ln_row<u16><<<LROWS, b256, 0, stream>>>(LAT, a_nl_s + l*DIM, a_nl_b + l*DIM, LMBUF);

    gemm64<4><<<dim3(8, 147), b256, 0, stream>>>(TBUF, WKVT, KVXB, nullptr, nullptr, MROWS, 1024, DIM, DIM, DIM);
    gemm64<4><<<dim3(12, 32), b256, 0, stream>>>(LMBUF, Wcat, QKVL, nullptr, nullptr, LROWS, 1536, DIM, DIM, DIM);

    vt_build<<<dim3(KPAD/32, 2, 128), b256, 0, stream>>>(KVXB, QKVL, VT);
    egemm<<<dim3(KPAD/128, 2, 128), b256, 0, stream>>>(QKVL, KVXB, EBUF);
    ogemm<<<dim3(256), b256, 0, stream>>>(EBUF, VT, AOBUF);

    gemm64<2><<<dim3(16, 32), b256, 0, stream>>>(AOBUF + (size_t)0, WOT, LAT, LAT, nullptr, LROWS, DIM, INNER, INNER, INNER);

    ln_row<u16><<<LROWS, b256, 0, stream>>>(LAT, f_n_s + l*DIM, f_n_b + l*DIM, LMBUF);
    gemm64<3><<<dim3(64, 32), b256, 0, stream>>>(LMBUF, W1T, HBUF, nullptr, nullptr, LROWS, FF, DIM, DIM, DIM);
    gemm64<5><<<dim3(16, 32, 2), b256, 0, stream>>>(HBUF, W2T, PART, nullptr, nullptr, LROWS, DIM, FF/2, FF, FF);
    combine_ffn<<<(LROWS*DIM/4)/256, b256, 0, stream>>>(PART, LAT);
  }

  ln_row<float><<<LROWS, b256, 0, stream>>>(LAT, out_n_s, out_n_b, (float*)d_out);
}